// Round 13
// baseline (67.777 us; speedup 1.0000x reference)
//
#include <hip/hip_runtime.h>
#include <hip/hip_bf16.h>
#include <stdint.h>

// Problem constants
#define BATCH 8
#define SEQ   2048
#define DEMB  1024
#define HD    64
#define NROWS (BATCH * SEQ)   // 16384
#define NSPL  8               // KV split factor

typedef __attribute__((ext_vector_type(8))) short bf16x8;  // 8 bf16 in 4 VGPRs
typedef __attribute__((ext_vector_type(4))) short s16x4;   // 4 bf16 (8 B)
typedef __attribute__((ext_vector_type(4))) float f32x4;

// fp32 -> bf16 round-to-nearest-even (bit pattern as short)
__device__ inline short f2b(float f) {
    unsigned u = __builtin_bit_cast(unsigned, f);
    unsigned r = (u + 0x7fffu + ((u >> 16) & 1u)) >> 16;
    return (short)r;
}
// native cast path (lets the compiler fuse pairs into v_cvt_pk_bf16_f32)
__device__ inline short f2bn(float f) {
    __hip_bfloat16 h(f);
    return __builtin_bit_cast(short, h);
}

// async global->LDS, 16 B per lane; dest = lds_base (wave-uniform) + lane*16
__device__ inline void gload_lds16(const void* g, void* l) {
    auto gp = reinterpret_cast<const __attribute__((address_space(1))) void*>(
        reinterpret_cast<uintptr_t>(g));
    auto lp = reinterpret_cast<__attribute__((address_space(3))) void*>(
        reinterpret_cast<uintptr_t>(l));
    __builtin_amdgcn_global_load_lds(gp, lp, 16, 0, 0);
}

// ---------------------------------------------------------------------------
// Kernel 0: prep — Wt[n][d] = W(d,n) as bf16; bias[192] fp32 concat
// ---------------------------------------------------------------------------
__global__ void prep_kernel(const float* __restrict__ Wq, const float* __restrict__ bq,
                            const float* __restrict__ Wk, const float* __restrict__ bk,
                            const float* __restrict__ Wv, const float* __restrict__ bv,
                            short* __restrict__ Wt, float* __restrict__ bias) {
    int idx = blockIdx.x * blockDim.x + threadIdx.x;   // 0 .. 192*1024-1
    if (idx < 192 * 1024) {
        int n = idx >> 10;
        int d = idx & 1023;
        const float* W = (n < 64) ? Wq : (n < 128) ? Wk : Wv;
        int nn = n & 63;
        Wt[idx] = f2b(W[(size_t)d * 64 + nn]);
    }
    if (idx < 192) {
        const float* bb = (idx < 64) ? bq : (idx < 128) ? bk : bv;
        bias[idx] = bb[idx & 63];
    }
}

// ---------------------------------------------------------------------------
// Kernel 1: QKV projection — LDS-staged double-buffered MFMA GEMM (r11, passing).
//   512 blocks (2/CU), BM=32, waves 2x2, 56KB LDS.
// ---------------------------------------------------------------------------
__global__ __launch_bounds__(256) void proj_kernel(const float* __restrict__ x,
        const short* __restrict__ Wt, const float* __restrict__ bias,
        short* __restrict__ Qo, short* __restrict__ Ko, short* __restrict__ Vto) {
    __shared__ short lA[2][32 * 64];    //  4 KB per buf (32 rows x 128 B)
    __shared__ short lB[2][192 * 64];   // 24 KB per buf (192 rows x 128 B)

    const int tid  = threadIdx.x;
    const int wid  = tid >> 6;
    const int lane = tid & 63;
    const int l15  = lane & 15;
    const int lg   = lane >> 4;
    const int row0 = blockIdx.x * 32;
    const int wr   = wid >> 1;          // 0..1: row half
    const int wc   = wid & 1;           // 0..1: col half

    const int sar = tid >> 4;   // 0..15: row-in-group for A staging
    const int sac = tid & 15;   // 16B chunk within 64-float k-window
    const int bn  = tid >> 3;   // 0..31: B row within round
    const int bc  = tid & 7;    // 16B chunk within 128-B B row

    f32x4 areg[2];

    auto loadA = [&](int k0) {
#pragma unroll
        for (int p = 0; p < 2; ++p) {
            int r = p * 16 + sar;
            areg[p] = *(const f32x4*)(x + (size_t)(row0 + r) * DEMB + k0 + sac * 4);
        }
    };
    auto writeA = [&](int bb) {
        char* base = (char*)lA[bb];
#pragma unroll
        for (int p = 0; p < 2; ++p) {
            int r = p * 16 + sar;
            int byte = r * 128 + ((sac * 8) ^ ((r & 7) << 4));
            s16x4 v;
            v[0] = f2b(areg[p][0]); v[1] = f2b(areg[p][1]);
            v[2] = f2b(areg[p][2]); v[3] = f2b(areg[p][3]);
            *(s16x4*)(base + byte) = v;
        }
    };
    auto stageB = [&](int k0, int bb) {
        const char* wb = (const char*)Wt;
#pragma unroll
        for (int j = 0; j < 6; ++j) {
            int n = j * 32 + bn;
            const char* src = wb + (size_t)n * 2048 + k0 * 2 + ((bc * 16) ^ ((n & 7) << 4));
            short* dst = lB[bb] + (size_t)(j * 256 + wid * 64) * 8;  // + lane*16B by HW
            gload_lds16(src, dst);
        }
    };

    f32x4 acc[6];
#pragma unroll
    for (int i = 0; i < 6; ++i) acc[i] = (f32x4){0.f, 0.f, 0.f, 0.f};

    loadA(0);
    stageB(0, 0);
    writeA(0);
    __syncthreads();

    int buf = 0;
    for (int ks = 0; ks < 16; ++ks) {
        if (ks < 15) { loadA((ks + 1) * 64); stageB((ks + 1) * 64, buf ^ 1); }

        const char* aB = (const char*)lA[buf];
        const char* bB = (const char*)lB[buf];
        const int ar = wr * 16 + l15;
        const int as = (ar & 7) << 4;
        bf16x8 a0 = *(const bf16x8*)(aB + ar * 128 + ((lg * 16) ^ as));
        bf16x8 a1 = *(const bf16x8*)(aB + ar * 128 + ((lg * 16 + 64) ^ as));
#pragma unroll
        for (int i = 0; i < 6; ++i) {
            int br = (wc * 6 + i) * 16 + l15;
            int bs = (br & 7) << 4;
            bf16x8 b0 = *(const bf16x8*)(bB + br * 128 + ((lg * 16) ^ bs));
            bf16x8 b1 = *(const bf16x8*)(bB + br * 128 + ((lg * 16 + 64) ^ bs));
            acc[i] = __builtin_amdgcn_mfma_f32_16x16x32_bf16(a0, b0, acc[i], 0, 0, 0);
            acc[i] = __builtin_amdgcn_mfma_f32_16x16x32_bf16(a1, b1, acc[i], 0, 0, 0);
        }

        if (ks < 15) writeA(buf ^ 1);
        __syncthreads();
        buf ^= 1;
    }

    // Epilogue: +bias, write bf16. C/D layout: col = l15, row = lg*4 + j.
    const int t0 = row0 + wr * 16;
#pragma unroll
    for (int i = 0; i < 6; ++i) {
        int n = (wc * 6 + i) * 16 + l15;
        float bv_ = bias[n];
#pragma unroll
        for (int j = 0; j < 4; ++j) {
            int t = t0 + lg * 4 + j;
            short v = f2b(acc[i][j] + bv_);
            if (n < 64) {
                Qo[(size_t)t * HD + n] = v;
            } else if (n < 128) {
                Ko[(size_t)t * HD + (n - 64)] = v;
            } else {
                int b = t >> 11, tt = t & 2047, d = n - 128;
                Vto[((size_t)b * HD + d) * SEQ + tt] = v;
            }
        }
    }
}

// ---------------------------------------------------------------------------
// Kernel 2: causal flash attention — r13: split-KV x8, 4 blocks/CU.
//   Grid: 8 b x 16 pairs x 8 split = 1024 blocks x 4 waves (4 blocks/CU,
//   4 waves/SIMD; r12 ran only 2/SIMD). Block (b,p,s): chunk g=p then g=31-p,
//   tiles t = s, s+8, ... (4-5 tiles per block, uniform).
//   LDS = 16K (K dbuf) + 16K (V dbuf) + 8K (P) = 40960 B exactly -> 4 blocks/CU.
//   P buffer is XOR-swizzled [4][16][64] (byte ^ (row&7)<<4 on both write and
//   read) instead of r12's padded [72] (which would push LDS past 40KB).
// ---------------------------------------------------------------------------
__global__ __launch_bounds__(256, 4) void attn_kernel(const short* __restrict__ Q,
        const short* __restrict__ K, const short* __restrict__ Vt,
        float* __restrict__ Opart, float* __restrict__ mlbuf) {
    __shared__ short lK[2][64 * 64];    // 8 KB per buf
    __shared__ short lV[2][64 * 64];    // 8 KB per buf
    __shared__ short plds[4][16][64];   // per-wave P transpose, XOR-swizzled

    const int tid  = threadIdx.x;
    const int wid  = tid >> 6;
    const int lane = tid & 63;
    const int l15  = lane & 15;
    const int lg   = lane >> 4;

    const int split = blockIdx.x & 7;
    const int pr    = (blockIdx.x >> 3) & 15;
    const int b     = blockIdx.x >> 7;

    const short* kbb = K  + (size_t)b * SEQ * HD;
    const short* vbb = Vt + (size_t)b * HD * SEQ;

    // staging lane decomposition: 8 rows x 8 chunks(16B) per issue
    const int srow = lane >> 3;
    const int schk = lane & 7;

    auto stageKV = [&](int kv0, int bb) {
#pragma unroll
        for (int i = 0; i < 2; ++i) {
            int rbase = wid * 16 + i * 8;
            int row   = rbase + srow;
            int swz   = (schk * 16) ^ ((row & 7) << 4);
            const char* ksrc = (const char*)(kbb + (size_t)(kv0 + row) * HD) + swz;
            const char* vsrc = (const char*)(vbb + (size_t)row * SEQ + kv0) + swz;
            gload_lds16(ksrc, &lK[bb][rbase * 64]);
            gload_lds16(vsrc, &lV[bb][rbase * 64]);
        }
    };

    const float SC = 0.18033688f;   // 0.125 * log2(e): softmax in base-2 domain
    char* pw = (char*)&plds[wid][0][0];

    for (int ci = 0; ci < 2; ++ci) {
        const int g     = ci ? (31 - pr) : pr;
        const int q0    = g * 64 + wid * 16;   // this wave's first q row
        const int ntile = g + 1;               // 64-wide kv tiles for this chunk

        // Q fragments for this chunk
        const short* qbase = Q + ((size_t)(b * SEQ + q0 + l15)) * HD + lg * 8;
        bf16x8 qf0 = *(const bf16x8*)(qbase);
        bf16x8 qf1 = *(const bf16x8*)(qbase + 32);

        f32x4 o[4];
        float m[4], lsum[4];
#pragma unroll
        for (int df = 0; df < 4; ++df) o[df] = (f32x4){0.f, 0.f, 0.f, 0.f};
#pragma unroll
        for (int j = 0; j < 4; ++j) { m[j] = -1e30f; lsum[j] = 0.f; }

        int t = split;
        if (t < ntile) stageKV(t * 64, 0);
        __syncthreads();   // vmcnt(0) drained before barrier => staging visible

        int buf = 0;
        for (; t < ntile; t += NSPL) {
            if (t + NSPL < ntile) stageKV((t + NSPL) * 64, buf ^ 1);

            const int kv0 = t * 64;
            const char* kB = (const char*)lK[buf];
            const char* vB = (const char*)lV[buf];

            // ---- S = Q K^T (4 col-frags x 2 k-steps) ----
            f32x4 s[4];
#pragma unroll
            for (int nf = 0; nf < 4; ++nf) s[nf] = (f32x4){0.f, 0.f, 0.f, 0.f};
#pragma unroll
            for (int nf = 0; nf < 4; ++nf) {
                int br = nf * 16 + l15;
                int bs = (br & 7) << 4;
                bf16x8 kf0 = *(const bf16x8*)(kB + br * 128 + ((lg * 16) ^ bs));
                bf16x8 kf1 = *(const bf16x8*)(kB + br * 128 + ((lg * 16 + 64) ^ bs));
                s[nf] = __builtin_amdgcn_mfma_f32_16x16x32_bf16(qf0, kf0, s[nf], 0, 0, 0);
                s[nf] = __builtin_amdgcn_mfma_f32_16x16x32_bf16(qf1, kf1, s[nf], 0, 0, 0);
            }

            // ---- scale (base-2 folded) + causal mask ----
            float sv[4][4];
#pragma unroll
            for (int nf = 0; nf < 4; ++nf)
#pragma unroll
                for (int j = 0; j < 4; ++j) {
                    int qr = q0 + lg * 4 + j;
                    int kv = kv0 + nf * 16 + l15;
                    float v = s[nf][j] * SC;
                    sv[nf][j] = (kv <= qr) ? v : -1e30f;
                }

            // ---- row max over the 64 kv of this tile ----
            float mt[4];
#pragma unroll
            for (int j = 0; j < 4; ++j)
                mt[j] = fmaxf(fmaxf(sv[0][j], sv[1][j]), fmaxf(sv[2][j], sv[3][j]));
#pragma unroll
            for (int sh = 1; sh < 16; sh <<= 1)
#pragma unroll
                for (int j = 0; j < 4; ++j) mt[j] = fmaxf(mt[j], __shfl_xor(mt[j], sh));

            // ---- online softmax update (exp2 domain, clamped) ----
            float p[4][4], rs[4];
#pragma unroll
            for (int j = 0; j < 4; ++j) {
                float mn = fmaxf(fmaxf(m[j], mt[j]), -1e20f);
                float sf = exp2f(m[j] - mn);
                m[j] = mn;
                lsum[j] *= sf;
#pragma unroll
                for (int df = 0; df < 4; ++df) o[df][j] *= sf;
#pragma unroll
                for (int nf = 0; nf < 4; ++nf) p[nf][j] = exp2f(sv[nf][j] - mn);
                rs[j] = (p[0][j] + p[1][j]) + (p[2][j] + p[3][j]);
            }
#pragma unroll
            for (int sh = 1; sh < 16; sh <<= 1)
#pragma unroll
                for (int j = 0; j < 4; ++j) rs[j] += __shfl_xor(rs[j], sh);
#pragma unroll
            for (int j = 0; j < 4; ++j) lsum[j] += rs[j];

            // ---- transpose P through LDS (per-wave, XOR-swizzled rows) ----
#pragma unroll
            for (int nf = 0; nf < 4; ++nf)
#pragma unroll
                for (int j = 0; j < 4; ++j) {
                    int r = lg * 4 + j;
                    int off = r * 128 + (nf * 16 + l15) * 2;
                    *(short*)(pw + (off ^ ((r & 7) << 4))) = f2bn(p[nf][j]);
                }

            int sw = (l15 & 7) << 4;
            bf16x8 pa0 = *(const bf16x8*)(pw + l15 * 128 + ((lg * 16) ^ sw));
            bf16x8 pa1 = *(const bf16x8*)(pw + l15 * 128 + ((lg * 16 + 64) ^ sw));

            // ---- O += P V (4 d-frags x 2 k-steps) ----
#pragma unroll
            for (int df = 0; df < 4; ++df) {
                int dr = df * 16 + l15;
                int ds = (dr & 7) << 4;
                bf16x8 vf0 = *(const bf16x8*)(vB + dr * 128 + ((lg * 16) ^ ds));
                bf16x8 vf1 = *(const bf16x8*)(vB + dr * 128 + ((lg * 16 + 64) ^ ds));
                o[df] = __builtin_amdgcn_mfma_f32_16x16x32_bf16(pa0, vf0, o[df], 0, 0, 0);
                o[df] = __builtin_amdgcn_mfma_f32_16x16x32_bf16(pa1, vf1, o[df], 0, 0, 0);
            }

            __syncthreads();   // all waves done with buf; next staging completed
            buf ^= 1;
        }

        // ---- epilogue: write unnormalized partials for this chunk ----
#pragma unroll
        for (int df = 0; df < 4; ++df) {
            int d = df * 16 + l15;
#pragma unroll
            for (int j = 0; j < 4; ++j) {
                size_t R = (size_t)b * SEQ + q0 + lg * 4 + j;
                Opart[((size_t)split * NROWS + R) * HD + d] = o[df][j];
            }
        }
        if (l15 == 0) {
#pragma unroll
            for (int j = 0; j < 4; ++j) {
                size_t R = (size_t)b * SEQ + q0 + lg * 4 + j;
                mlbuf[((size_t)split * NROWS + R) * 2 + 0] = m[j];
                mlbuf[((size_t)split * NROWS + R) * 2 + 1] = lsum[j];
            }
        }
    }
}

// ---------------------------------------------------------------------------
// Kernel 3: merge 8 KV-split partials -> normalized output (exp2 domain).
// ---------------------------------------------------------------------------
__global__ __launch_bounds__(256) void merge_kernel(const float* __restrict__ Opart,
        const float* __restrict__ mlbuf, float* __restrict__ out) {
    int tg = blockIdx.x * 256 + threadIdx.x;   // 0 .. 262143
    int rr = tg >> 4;
    int fc = tg & 15;

    float mv[NSPL], lv[NSPL];
    float M = -3e38f;
#pragma unroll
    for (int i = 0; i < NSPL; ++i) {
        mv[i] = mlbuf[((size_t)i * NROWS + rr) * 2 + 0];
        lv[i] = mlbuf[((size_t)i * NROWS + rr) * 2 + 1];
        M = fmaxf(M, mv[i]);
    }
    float L = 0.f;
    f32x4 acc = (f32x4){0.f, 0.f, 0.f, 0.f};
#pragma unroll
    for (int i = 0; i < NSPL; ++i) {
        float w = exp2f(mv[i] - M);
        L += lv[i] * w;
        f32x4 v = *(const f32x4*)(Opart + ((size_t)i * NROWS + rr) * HD + fc * 4);
        acc += v * w;
    }
    f32x4 r = acc / L;
    *(f32x4*)(out + (size_t)rr * HD + fc * 4) = r;
}

// ---------------------------------------------------------------------------
extern "C" void kernel_launch(void* const* d_in, const int* in_sizes, int n_in,
                              void* d_out, int out_size, void* d_ws, size_t ws_size,
                              hipStream_t stream) {
    const float* x  = (const float*)d_in[0];
    const float* Wq = (const float*)d_in[1];
    const float* bq = (const float*)d_in[2];
    const float* Wk = (const float*)d_in[3];
    const float* bk = (const float*)d_in[4];
    const float* Wv = (const float*)d_in[5];
    const float* bv = (const float*)d_in[6];
    float* out = (float*)d_out;

    char* ws = (char*)d_ws;
    // Workspace layout (bytes):
    //   Wt    bf16 [192][1024]        @ 0         (393216)
    //   bias  f32  [192]              @ 393216    (768, pad to 394240)
    //   Q     bf16 [16384][64]        @ 394240    (2097152)
    //   K     bf16 [16384][64]        @ 2491392   (2097152)
    //   Vt    bf16 [8][64][2048]      @ 4588544   (2097152)
    //   Opart f32  [8][16384][64]     @ 6685696   (33554432)
    //   ml    f32  [8][16384][2]      @ 40240128  (1048576)   end 41288704
    short* Wt   = (short*)(ws);
    float* bias = (float*)(ws + 393216);
    short* Qb   = (short*)(ws + 394240);
    short* Kb   = (short*)(ws + 394240 + 2097152);
    short* Vtb  = (short*)(ws + 394240 + 2 * 2097152);
    float* Op   = (float*)(ws + 6685696);
    float* ml   = (float*)(ws + 40240128);

    hipLaunchKernelGGL(prep_kernel, dim3(768), dim3(256), 0, stream,
                       Wq, bq, Wk, bk, Wv, bv, Wt, bias);
    hipLaunchKernelGGL(proj_kernel, dim3(512), dim3(256), 0, stream,
                       x, Wt, bias, Qb, Kb, Vtb);
    hipLaunchKernelGGL(attn_kernel, dim3(1024), dim3(256), 0, stream,
                       Qb, Kb, Vtb, Op, ml);
    hipLaunchKernelGGL(merge_kernel, dim3(1024), dim3(256), 0, stream,
                       Op, ml, out);
}

// Round 14
// 53.868 us; speedup vs baseline: 1.2582x; 1.2582x over previous
//
#include <hip/hip_runtime.h>
#include <hip/hip_bf16.h>
#include <stdint.h>

// Problem constants
#define BATCH 8
#define SEQ   2048
#define DEMB  1024
#define HD    64
#define NROWS (BATCH * SEQ)   // 16384
#define NSPL  4               // KV split factor

typedef __attribute__((ext_vector_type(8))) short bf16x8;  // 8 bf16 in 4 VGPRs
typedef __attribute__((ext_vector_type(4))) short s16x4;   // 4 bf16 (8 B)
typedef __attribute__((ext_vector_type(4))) float f32x4;

// fp32 -> bf16 round-to-nearest-even (bit pattern as short)
__device__ inline short f2b(float f) {
    unsigned u = __builtin_bit_cast(unsigned, f);
    unsigned r = (u + 0x7fffu + ((u >> 16) & 1u)) >> 16;
    return (short)r;
}
// native cast path (compiler can fuse pairs into v_cvt_pk_bf16_f32)
__device__ inline short f2bn(float f) {
    __hip_bfloat16 h(f);
    return __builtin_bit_cast(short, h);
}

// async global->LDS, 16 B per lane; dest = lds_base (wave-uniform) + lane*16
__device__ inline void gload_lds16(const void* g, void* l) {
    auto gp = reinterpret_cast<const __attribute__((address_space(1))) void*>(
        reinterpret_cast<uintptr_t>(g));
    auto lp = reinterpret_cast<__attribute__((address_space(3))) void*>(
        reinterpret_cast<uintptr_t>(l));
    __builtin_amdgcn_global_load_lds(gp, lp, 16, 0, 0);
}

// ---------------------------------------------------------------------------
// Kernel 0: prep — Wt[n][d] = W(d,n) as bf16; bias[192] fp32 concat
// ---------------------------------------------------------------------------
__global__ void prep_kernel(const float* __restrict__ Wq, const float* __restrict__ bq,
                            const float* __restrict__ Wk, const float* __restrict__ bk,
                            const float* __restrict__ Wv, const float* __restrict__ bv,
                            short* __restrict__ Wt, float* __restrict__ bias) {
    int idx = blockIdx.x * blockDim.x + threadIdx.x;   // 0 .. 192*1024-1
    if (idx < 192 * 1024) {
        int n = idx >> 10;
        int d = idx & 1023;
        const float* W = (n < 64) ? Wq : (n < 128) ? Wk : Wv;
        int nn = n & 63;
        Wt[idx] = f2b(W[(size_t)d * 64 + nn]);
    }
    if (idx < 192) {
        const float* bb = (idx < 64) ? bq : (idx < 128) ? bk : bv;
        bias[idx] = bb[idx & 63];
    }
}

// ---------------------------------------------------------------------------
// Kernel 1: QKV projection — LDS-staged double-buffered MFMA GEMM (r11, passing).
//   512 blocks (2/CU), BM=32, waves 2x2, 56KB LDS.
// ---------------------------------------------------------------------------
__global__ __launch_bounds__(256) void proj_kernel(const float* __restrict__ x,
        const short* __restrict__ Wt, const float* __restrict__ bias,
        short* __restrict__ Qo, short* __restrict__ Ko, short* __restrict__ Vto) {
    __shared__ short lA[2][32 * 64];    //  4 KB per buf (32 rows x 128 B)
    __shared__ short lB[2][192 * 64];   // 24 KB per buf (192 rows x 128 B)

    const int tid  = threadIdx.x;
    const int wid  = tid >> 6;
    const int lane = tid & 63;
    const int l15  = lane & 15;
    const int lg   = lane >> 4;
    const int row0 = blockIdx.x * 32;
    const int wr   = wid >> 1;          // 0..1: row half
    const int wc   = wid & 1;           // 0..1: col half

    const int sar = tid >> 4;   // 0..15: row-in-group for A staging
    const int sac = tid & 15;   // 16B chunk within 64-float k-window
    const int bn  = tid >> 3;   // 0..31: B row within round
    const int bc  = tid & 7;    // 16B chunk within 128-B B row

    f32x4 areg[2];

    auto loadA = [&](int k0) {
#pragma unroll
        for (int p = 0; p < 2; ++p) {
            int r = p * 16 + sar;
            areg[p] = *(const f32x4*)(x + (size_t)(row0 + r) * DEMB + k0 + sac * 4);
        }
    };
    auto writeA = [&](int bb) {
        char* base = (char*)lA[bb];
#pragma unroll
        for (int p = 0; p < 2; ++p) {
            int r = p * 16 + sar;
            int byte = r * 128 + ((sac * 8) ^ ((r & 7) << 4));
            s16x4 v;
            v[0] = f2b(areg[p][0]); v[1] = f2b(areg[p][1]);
            v[2] = f2b(areg[p][2]); v[3] = f2b(areg[p][3]);
            *(s16x4*)(base + byte) = v;
        }
    };
    auto stageB = [&](int k0, int bb) {
        const char* wb = (const char*)Wt;
#pragma unroll
        for (int j = 0; j < 6; ++j) {
            int n = j * 32 + bn;
            const char* src = wb + (size_t)n * 2048 + k0 * 2 + ((bc * 16) ^ ((n & 7) << 4));
            short* dst = lB[bb] + (size_t)(j * 256 + wid * 64) * 8;  // + lane*16B by HW
            gload_lds16(src, dst);
        }
    };

    f32x4 acc[6];
#pragma unroll
    for (int i = 0; i < 6; ++i) acc[i] = (f32x4){0.f, 0.f, 0.f, 0.f};

    loadA(0);
    stageB(0, 0);
    writeA(0);
    __syncthreads();

    int buf = 0;
    for (int ks = 0; ks < 16; ++ks) {
        if (ks < 15) { loadA((ks + 1) * 64); stageB((ks + 1) * 64, buf ^ 1); }

        const char* aB = (const char*)lA[buf];
        const char* bB = (const char*)lB[buf];
        const int ar = wr * 16 + l15;
        const int as = (ar & 7) << 4;
        bf16x8 a0 = *(const bf16x8*)(aB + ar * 128 + ((lg * 16) ^ as));
        bf16x8 a1 = *(const bf16x8*)(aB + ar * 128 + ((lg * 16 + 64) ^ as));
#pragma unroll
        for (int i = 0; i < 6; ++i) {
            int br = (wc * 6 + i) * 16 + l15;
            int bs = (br & 7) << 4;
            bf16x8 b0 = *(const bf16x8*)(bB + br * 128 + ((lg * 16) ^ bs));
            bf16x8 b1 = *(const bf16x8*)(bB + br * 128 + ((lg * 16 + 64) ^ bs));
            acc[i] = __builtin_amdgcn_mfma_f32_16x16x32_bf16(a0, b0, acc[i], 0, 0, 0);
            acc[i] = __builtin_amdgcn_mfma_f32_16x16x32_bf16(a1, b1, acc[i], 0, 0, 0);
        }

        if (ks < 15) writeA(buf ^ 1);
        __syncthreads();
        buf ^= 1;
    }

    // Epilogue: +bias, write bf16. C/D layout: col = l15, row = lg*4 + j.
    const int t0 = row0 + wr * 16;
#pragma unroll
    for (int i = 0; i < 6; ++i) {
        int n = (wc * 6 + i) * 16 + l15;
        float bv_ = bias[n];
#pragma unroll
        for (int j = 0; j < 4; ++j) {
            int t = t0 + lg * 4 + j;
            short v = f2b(acc[i][j] + bv_);
            if (n < 64) {
                Qo[(size_t)t * HD + n] = v;
            } else if (n < 128) {
                Ko[(size_t)t * HD + (n - 64)] = v;
            } else {
                int b = t >> 11, tt = t & 2047, d = n - 128;
                Vto[((size_t)b * HD + d) * SEQ + tt] = v;
            }
        }
    }
}

// ---------------------------------------------------------------------------
// Kernel 2: causal flash attention — r14: SWAPPED QK^T (S^T = K·Q^T) so each
//   lane owns one q-row; row reduces are 15 in-lane ops + 2 shfl_xor (was 32
//   ds_bpermute/tile). Online state (m,l) is scalar per lane. P packed to LDS
//   with 4x ds_write_b64 (XOR-swizzled), read back as PV B-operand; PV
//   computes O^T = mfma(Vt, P). Split-KV x4 (r12 config — r13's x8 traffic
//   regression reverted), g<->31-p pairing, KVBLK=64 double-buffered staging.
//   Grid: 8 b x 16 pairs x 4 split = 512 blocks x 4 waves. LDS 40960 B.
// ---------------------------------------------------------------------------
__global__ __launch_bounds__(256, 4) void attn_kernel(const short* __restrict__ Q,
        const short* __restrict__ K, const short* __restrict__ Vt,
        float* __restrict__ Opart, float* __restrict__ mlbuf) {
    __shared__ short lK[2][64 * 64];    // 8 KB per buf
    __shared__ short lV[2][64 * 64];    // 8 KB per buf
    __shared__ short plds[4][16][64];   // per-wave P (row=q, col=kv), swizzled

    const int tid  = threadIdx.x;
    const int wid  = tid >> 6;
    const int lane = tid & 63;
    const int l15  = lane & 15;
    const int lg   = lane >> 4;

    const int split = blockIdx.x & 3;
    const int pr    = (blockIdx.x >> 2) & 15;
    const int b     = blockIdx.x >> 6;

    const short* kbb = K  + (size_t)b * SEQ * HD;
    const short* vbb = Vt + (size_t)b * HD * SEQ;

    // staging lane decomposition: 8 rows x 8 chunks(16B) per issue
    const int srow = lane >> 3;
    const int schk = lane & 7;

    auto stageKV = [&](int kv0, int bb) {
#pragma unroll
        for (int i = 0; i < 2; ++i) {
            int rbase = wid * 16 + i * 8;
            int row   = rbase + srow;
            int swz   = (schk * 16) ^ ((row & 7) << 4);
            const char* ksrc = (const char*)(kbb + (size_t)(kv0 + row) * HD) + swz;
            const char* vsrc = (const char*)(vbb + (size_t)row * SEQ + kv0) + swz;
            gload_lds16(ksrc, &lK[bb][rbase * 64]);
            gload_lds16(vsrc, &lV[bb][rbase * 64]);
        }
    };

    const float SC = 0.18033688f;   // 0.125 * log2(e): softmax in base-2 domain
    char* pw = (char*)&plds[wid][0][0];
    const int sw = (l15 & 7) << 4;  // this lane's P-row swizzle

    for (int ci = 0; ci < 2; ++ci) {
        const int g     = ci ? (31 - pr) : pr;
        const int q0    = g * 64 + wid * 16;   // this wave's first q row
        const int ntile = g + 1;               // 64-wide kv tiles for this chunk
        const int qr    = q0 + l15;            // this lane's q row

        // Q fragments for this chunk
        const short* qbase = Q + ((size_t)(b * SEQ + qr)) * HD + lg * 8;
        bf16x8 qf0 = *(const bf16x8*)(qbase);
        bf16x8 qf1 = *(const bf16x8*)(qbase + 32);

        f32x4 o[4];   // o[df][j] = O[q=l15][d = df*16 + lg*4 + j]
        float m = -1e30f, lsum = 0.f;
#pragma unroll
        for (int df = 0; df < 4; ++df) o[df] = (f32x4){0.f, 0.f, 0.f, 0.f};

        int t = split;
        if (t < ntile) stageKV(t * 64, 0);
        __syncthreads();   // vmcnt(0) drained before barrier => staging visible

        int buf = 0;
        for (; t < ntile; t += NSPL) {
            if (t + NSPL < ntile) stageKV((t + NSPL) * 64, buf ^ 1);

            const int kv0 = t * 64;
            const char* kB = (const char*)lK[buf];
            const char* vB = (const char*)lV[buf];

            // ---- S^T = K Q^T: s[nf] holds col=q(l15), row=kv(nf*16+lg*4+j) ----
            f32x4 s[4];
#pragma unroll
            for (int nf = 0; nf < 4; ++nf) s[nf] = (f32x4){0.f, 0.f, 0.f, 0.f};
#pragma unroll
            for (int nf = 0; nf < 4; ++nf) {
                int br = nf * 16 + l15;
                int bs = (br & 7) << 4;
                bf16x8 kf0 = *(const bf16x8*)(kB + br * 128 + ((lg * 16) ^ bs));
                bf16x8 kf1 = *(const bf16x8*)(kB + br * 128 + ((lg * 16 + 64) ^ bs));
                s[nf] = __builtin_amdgcn_mfma_f32_16x16x32_bf16(kf0, qf0, s[nf], 0, 0, 0);
                s[nf] = __builtin_amdgcn_mfma_f32_16x16x32_bf16(kf1, qf1, s[nf], 0, 0, 0);
            }

            // ---- scale; mask only on the diagonal tile ----
            float sv[4][4];
            if (t == g) {
#pragma unroll
                for (int nf = 0; nf < 4; ++nf)
#pragma unroll
                    for (int j = 0; j < 4; ++j) {
                        int kv = kv0 + nf * 16 + lg * 4 + j;
                        float v = s[nf][j] * SC;
                        sv[nf][j] = (kv <= qr) ? v : -1e30f;
                    }
            } else {
#pragma unroll
                for (int nf = 0; nf < 4; ++nf)
#pragma unroll
                    for (int j = 0; j < 4; ++j) sv[nf][j] = s[nf][j] * SC;
            }

            // ---- row max: 15 in-lane + 2 cross-lg shuffles ----
            float m4[4];
#pragma unroll
            for (int nf = 0; nf < 4; ++nf)
                m4[nf] = fmaxf(fmaxf(sv[nf][0], sv[nf][1]), fmaxf(sv[nf][2], sv[nf][3]));
            float mt = fmaxf(fmaxf(m4[0], m4[1]), fmaxf(m4[2], m4[3]));
            mt = fmaxf(mt, __shfl_xor(mt, 16));
            mt = fmaxf(mt, __shfl_xor(mt, 32));

            // ---- online update (exp2 domain, scalar state) ----
            float mn = fmaxf(fmaxf(m, mt), -1e20f);
            float sf = exp2f(m - mn);
            m = mn;
            lsum *= sf;
#pragma unroll
            for (int df = 0; df < 4; ++df) o[df] *= sf;

            float p[4][4], rsum = 0.f;
#pragma unroll
            for (int nf = 0; nf < 4; ++nf) {
                float r4 = 0.f;
#pragma unroll
                for (int j = 0; j < 4; ++j) {
                    p[nf][j] = exp2f(sv[nf][j] - mn);
                    r4 += p[nf][j];
                }
                rsum += r4;
            }
            rsum += __shfl_xor(rsum, 16);
            rsum += __shfl_xor(rsum, 32);
            lsum += rsum;

            // ---- pack P (own q-row) into LDS: 4x ds_write_b64, swizzled ----
#pragma unroll
            for (int nf = 0; nf < 4; ++nf) {
                s16x4 pv;
                pv[0] = f2bn(p[nf][0]); pv[1] = f2bn(p[nf][1]);
                pv[2] = f2bn(p[nf][2]); pv[3] = f2bn(p[nf][3]);
                int off = (nf * 16 + lg * 4) * 2;
                *(s16x4*)(pw + l15 * 128 + (off ^ sw)) = pv;
            }

            bf16x8 pa0 = *(const bf16x8*)(pw + l15 * 128 + ((lg * 16) ^ sw));
            bf16x8 pa1 = *(const bf16x8*)(pw + l15 * 128 + ((lg * 16 + 64) ^ sw));

            // ---- O^T += V^T P^T (4 d-frags x 2 k-halves) ----
#pragma unroll
            for (int df = 0; df < 4; ++df) {
                int dr = df * 16 + l15;
                int ds = (dr & 7) << 4;
                bf16x8 vf0 = *(const bf16x8*)(vB + dr * 128 + ((lg * 16) ^ ds));
                bf16x8 vf1 = *(const bf16x8*)(vB + dr * 128 + ((lg * 16 + 64) ^ ds));
                o[df] = __builtin_amdgcn_mfma_f32_16x16x32_bf16(vf0, pa0, o[df], 0, 0, 0);
                o[df] = __builtin_amdgcn_mfma_f32_16x16x32_bf16(vf1, pa1, o[df], 0, 0, 0);
            }

            __syncthreads();   // all waves done with buf; next staging completed
            buf ^= 1;
        }

        // ---- epilogue: unnormalized partials; lane owns q-row qr ----
        {
            size_t R = (size_t)b * SEQ + qr;
            float* op = Opart + ((size_t)split * NROWS + R) * HD;
#pragma unroll
            for (int df = 0; df < 4; ++df)
                *(f32x4*)(op + df * 16 + lg * 4) = o[df];
            if (lg == 0) {
                mlbuf[((size_t)split * NROWS + R) * 2 + 0] = m;
                mlbuf[((size_t)split * NROWS + R) * 2 + 1] = lsum;
            }
        }
    }
}

// ---------------------------------------------------------------------------
// Kernel 3: merge 4 KV-split partials -> normalized output (exp2 domain).
// ---------------------------------------------------------------------------
__global__ __launch_bounds__(256) void merge_kernel(const float* __restrict__ Opart,
        const float* __restrict__ mlbuf, float* __restrict__ out) {
    int tg = blockIdx.x * 256 + threadIdx.x;   // 0 .. 262143
    int rr = tg >> 4;
    int fc = tg & 15;

    float mv[NSPL], lv[NSPL];
    float M = -3e38f;
#pragma unroll
    for (int i = 0; i < NSPL; ++i) {
        mv[i] = mlbuf[((size_t)i * NROWS + rr) * 2 + 0];
        lv[i] = mlbuf[((size_t)i * NROWS + rr) * 2 + 1];
        M = fmaxf(M, mv[i]);
    }
    float L = 0.f;
    f32x4 acc = (f32x4){0.f, 0.f, 0.f, 0.f};
#pragma unroll
    for (int i = 0; i < NSPL; ++i) {
        float w = exp2f(mv[i] - M);
        L += lv[i] * w;
        f32x4 v = *(const f32x4*)(Opart + ((size_t)i * NROWS + rr) * HD + fc * 4);
        acc += v * w;
    }
    f32x4 r = acc / L;
    *(f32x4*)(out + (size_t)rr * HD + fc * 4) = r;
}

// ---------------------------------------------------------------------------
extern "C" void kernel_launch(void* const* d_in, const int* in_sizes, int n_in,
                              void* d_out, int out_size, void* d_ws, size_t ws_size,
                              hipStream_t stream) {
    const float* x  = (const float*)d_in[0];
    const float* Wq = (const float*)d_in[1];
    const float* bq = (const float*)d_in[2];
    const float* Wk = (const float*)d_in[3];
    const float* bk = (const float*)d_in[4];
    const float* Wv = (const float*)d_in[5];
    const float* bv = (const float*)d_in[6];
    float* out = (float*)d_out;

    char* ws = (char*)d_ws;
    // Workspace layout (bytes):
    //   Wt    bf16 [192][1024]        @ 0         (393216)
    //   bias  f32  [192]              @ 393216    (768, pad to 394240)
    //   Q     bf16 [16384][64]        @ 394240    (2097152)
    //   K     bf16 [16384][64]        @ 2491392   (2097152)
    //   Vt    bf16 [8][64][2048]      @ 4588544   (2097152)
    //   Opart f32  [4][16384][64]     @ 6685696   (16777216)
    //   ml    f32  [4][16384][2]      @ 23462912  (524288)   end 23987200
    short* Wt   = (short*)(ws);
    float* bias = (float*)(ws + 393216);
    short* Qb   = (short*)(ws + 394240);
    short* Kb   = (short*)(ws + 394240 + 2097152);
    short* Vtb  = (short*)(ws + 394240 + 2 * 2097152);
    float* Op   = (float*)(ws + 6685696);
    float* ml   = (float*)(ws + 23462912);

    hipLaunchKernelGGL(prep_kernel, dim3(768), dim3(256), 0, stream,
                       Wq, bq, Wk, bk, Wv, bv, Wt, bias);
    hipLaunchKernelGGL(proj_kernel, dim3(512), dim3(256), 0, stream,
                       x, Wt, bias, Qb, Kb, Vtb);
    hipLaunchKernelGGL(attn_kernel, dim3(512), dim3(256), 0, stream,
                       Qb, Kb, Vtb, Op, ml);
    hipLaunchKernelGGL(merge_kernel, dim3(1024), dim3(256), 0, stream,
                       Op, ml, out);
}

// Round 15
// 51.473 us; speedup vs baseline: 1.3168x; 1.0465x over previous
//
#include <hip/hip_runtime.h>
#include <hip/hip_bf16.h>
#include <stdint.h>

// Problem constants
#define BATCH 8
#define SEQ   2048
#define DEMB  1024
#define HD    64
#define NROWS (BATCH * SEQ)   // 16384
#define NSPL  4               // KV split factor

typedef __attribute__((ext_vector_type(8))) short bf16x8;  // 8 bf16 in 4 VGPRs
typedef __attribute__((ext_vector_type(4))) short s16x4;   // 4 bf16 (8 B)
typedef __attribute__((ext_vector_type(4))) float f32x4;

// fp32 -> bf16 round-to-nearest-even (bit pattern as short)
__device__ inline short f2b(float f) {
    unsigned u = __builtin_bit_cast(unsigned, f);
    unsigned r = (u + 0x7fffu + ((u >> 16) & 1u)) >> 16;
    return (short)r;
}
// native cast path (compiler can fuse pairs into v_cvt_pk_bf16_f32)
__device__ inline short f2bn(float f) {
    __hip_bfloat16 h(f);
    return __builtin_bit_cast(short, h);
}

// async global->LDS, 16 B per lane; dest = lds_base (wave-uniform) + lane*16
__device__ inline void gload_lds16(const void* g, void* l) {
    auto gp = reinterpret_cast<const __attribute__((address_space(1))) void*>(
        reinterpret_cast<uintptr_t>(g));
    auto lp = reinterpret_cast<__attribute__((address_space(3))) void*>(
        reinterpret_cast<uintptr_t>(l));
    __builtin_amdgcn_global_load_lds(gp, lp, 16, 0, 0);
}

// ---------------------------------------------------------------------------
// Kernel 0: prep — Wt[n][d] = W(d,n) as bf16; bias[192] fp32 concat
// ---------------------------------------------------------------------------
__global__ void prep_kernel(const float* __restrict__ Wq, const float* __restrict__ bq,
                            const float* __restrict__ Wk, const float* __restrict__ bk,
                            const float* __restrict__ Wv, const float* __restrict__ bv,
                            short* __restrict__ Wt, float* __restrict__ bias) {
    int idx = blockIdx.x * blockDim.x + threadIdx.x;   // 0 .. 192*1024-1
    if (idx < 192 * 1024) {
        int n = idx >> 10;
        int d = idx & 1023;
        const float* W = (n < 64) ? Wq : (n < 128) ? Wk : Wv;
        int nn = n & 63;
        Wt[idx] = f2b(W[(size_t)d * 64 + nn]);
    }
    if (idx < 192) {
        const float* bb = (idx < 64) ? bq : (idx < 128) ? bk : bv;
        bias[idx] = bb[idx & 63];
    }
}

// ---------------------------------------------------------------------------
// Kernel 1: QKV projection — r15: N-split for occupancy.
//   BM=32, BN=96. Grid = 1024 blocks: bid = c*512 + r (c = col-block 0..1,
//   r = row-block 0..511). Same-row col-blocks are 512 apart -> same XCD
//   (512%8==0) -> x rows shared via that XCD's L2.
//   LDS = 2*(4KB A + 12KB B) = 32KB -> 4 blocks/CU (was 2 at 56KB), i.e.
//   4 waves/SIMD to hide the barrier-locked staging latency.
//   Wave (wr,wc): rows wr*16..+16, col frags wc*3..+3 (48 cols, 6 MFMA/k-step).
//   Staging machinery identical to r11 (A reg-stage + swizzled ds_write;
//   B global_load_lds from pre-swizzled source; involution on both sides).
// ---------------------------------------------------------------------------
__global__ __launch_bounds__(256) void proj_kernel(const float* __restrict__ x,
        const short* __restrict__ Wt, const float* __restrict__ bias,
        short* __restrict__ Qo, short* __restrict__ Ko, short* __restrict__ Vto) {
    __shared__ short lA[2][32 * 64];    //  4 KB per buf (32 rows x 128 B)
    __shared__ short lB[2][96 * 64];    // 12 KB per buf (96 rows x 128 B)

    const int tid  = threadIdx.x;
    const int wid  = tid >> 6;
    const int lane = tid & 63;
    const int l15  = lane & 15;
    const int lg   = lane >> 4;
    const int cb   = blockIdx.x >> 9;        // col-block 0..1
    const int row0 = (blockIdx.x & 511) * 32;
    const int n0   = cb * 96;                // first output col of this block
    const int wr   = wid >> 1;               // 0..1: row half
    const int wc   = wid & 1;                // 0..1: col half

    const int sar = tid >> 4;   // 0..15: row-in-group for A staging
    const int sac = tid & 15;   // 16B chunk within 64-float k-window
    const int bn  = tid >> 3;   // 0..31: B row within round
    const int bc  = tid & 7;    // 16B chunk within 128-B B row

    f32x4 areg[2];

    auto loadA = [&](int k0) {
#pragma unroll
        for (int p = 0; p < 2; ++p) {
            int r = p * 16 + sar;
            areg[p] = *(const f32x4*)(x + (size_t)(row0 + r) * DEMB + k0 + sac * 4);
        }
    };
    auto writeA = [&](int bb) {
        char* base = (char*)lA[bb];
#pragma unroll
        for (int p = 0; p < 2; ++p) {
            int r = p * 16 + sar;
            int byte = r * 128 + ((sac * 8) ^ ((r & 7) << 4));
            s16x4 v;
            v[0] = f2b(areg[p][0]); v[1] = f2b(areg[p][1]);
            v[2] = f2b(areg[p][2]); v[3] = f2b(areg[p][3]);
            *(s16x4*)(base + byte) = v;
        }
    };
    auto stageB = [&](int k0, int bb) {
        const char* wb = (const char*)Wt;
#pragma unroll
        for (int j = 0; j < 3; ++j) {
            int nl = j * 32 + bn;            // local B row 0..95
            const char* src = wb + (size_t)(n0 + nl) * 2048 + k0 * 2
                              + ((bc * 16) ^ ((nl & 7) << 4));
            short* dst = lB[bb] + (size_t)(j * 2048 + wid * 512); // + lane*16B by HW
            gload_lds16(src, dst);
        }
    };

    f32x4 acc[3];
#pragma unroll
    for (int i = 0; i < 3; ++i) acc[i] = (f32x4){0.f, 0.f, 0.f, 0.f};

    loadA(0);
    stageB(0, 0);
    writeA(0);
    __syncthreads();

    int buf = 0;
    for (int ks = 0; ks < 16; ++ks) {
        if (ks < 15) { loadA((ks + 1) * 64); stageB((ks + 1) * 64, buf ^ 1); }

        const char* aB = (const char*)lA[buf];
        const char* bB = (const char*)lB[buf];
        const int ar = wr * 16 + l15;
        const int as = (ar & 7) << 4;
        bf16x8 a0 = *(const bf16x8*)(aB + ar * 128 + ((lg * 16) ^ as));
        bf16x8 a1 = *(const bf16x8*)(aB + ar * 128 + ((lg * 16 + 64) ^ as));
#pragma unroll
        for (int i = 0; i < 3; ++i) {
            int br = wc * 48 + i * 16 + l15;   // local B row 0..95
            int bs = (br & 7) << 4;
            bf16x8 b0 = *(const bf16x8*)(bB + br * 128 + ((lg * 16) ^ bs));
            bf16x8 b1 = *(const bf16x8*)(bB + br * 128 + ((lg * 16 + 64) ^ bs));
            acc[i] = __builtin_amdgcn_mfma_f32_16x16x32_bf16(a0, b0, acc[i], 0, 0, 0);
            acc[i] = __builtin_amdgcn_mfma_f32_16x16x32_bf16(a1, b1, acc[i], 0, 0, 0);
        }

        if (ks < 15) writeA(buf ^ 1);
        __syncthreads();
        buf ^= 1;
    }

    // Epilogue: +bias, write bf16. C/D layout: col = l15, row = lg*4 + j.
    const int t0 = row0 + wr * 16;
#pragma unroll
    for (int i = 0; i < 3; ++i) {
        int n = n0 + wc * 48 + i * 16 + l15;
        float bv_ = bias[n];
#pragma unroll
        for (int j = 0; j < 4; ++j) {
            int t = t0 + lg * 4 + j;
            short v = f2b(acc[i][j] + bv_);
            if (n < 64) {
                Qo[(size_t)t * HD + n] = v;
            } else if (n < 128) {
                Ko[(size_t)t * HD + (n - 64)] = v;
            } else {
                int b = t >> 11, tt = t & 2047, d = n - 128;
                Vto[((size_t)b * HD + d) * SEQ + tt] = v;
            }
        }
    }
}

// ---------------------------------------------------------------------------
// Kernel 2: causal flash attention — swapped QK^T (r14, passing, unchanged).
// ---------------------------------------------------------------------------
__global__ __launch_bounds__(256, 4) void attn_kernel(const short* __restrict__ Q,
        const short* __restrict__ K, const short* __restrict__ Vt,
        float* __restrict__ Opart, float* __restrict__ mlbuf) {
    __shared__ short lK[2][64 * 64];    // 8 KB per buf
    __shared__ short lV[2][64 * 64];    // 8 KB per buf
    __shared__ short plds[4][16][64];   // per-wave P (row=q, col=kv), swizzled

    const int tid  = threadIdx.x;
    const int wid  = tid >> 6;
    const int lane = tid & 63;
    const int l15  = lane & 15;
    const int lg   = lane >> 4;

    const int split = blockIdx.x & 3;
    const int pr    = (blockIdx.x >> 2) & 15;
    const int b     = blockIdx.x >> 6;

    const short* kbb = K  + (size_t)b * SEQ * HD;
    const short* vbb = Vt + (size_t)b * HD * SEQ;

    // staging lane decomposition: 8 rows x 8 chunks(16B) per issue
    const int srow = lane >> 3;
    const int schk = lane & 7;

    auto stageKV = [&](int kv0, int bb) {
#pragma unroll
        for (int i = 0; i < 2; ++i) {
            int rbase = wid * 16 + i * 8;
            int row   = rbase + srow;
            int swz   = (schk * 16) ^ ((row & 7) << 4);
            const char* ksrc = (const char*)(kbb + (size_t)(kv0 + row) * HD) + swz;
            const char* vsrc = (const char*)(vbb + (size_t)row * SEQ + kv0) + swz;
            gload_lds16(ksrc, &lK[bb][rbase * 64]);
            gload_lds16(vsrc, &lV[bb][rbase * 64]);
        }
    };

    const float SC = 0.18033688f;   // 0.125 * log2(e): softmax in base-2 domain
    char* pw = (char*)&plds[wid][0][0];
    const int sw = (l15 & 7) << 4;  // this lane's P-row swizzle

    for (int ci = 0; ci < 2; ++ci) {
        const int g     = ci ? (31 - pr) : pr;
        const int q0    = g * 64 + wid * 16;   // this wave's first q row
        const int ntile = g + 1;               // 64-wide kv tiles for this chunk
        const int qr    = q0 + l15;            // this lane's q row

        // Q fragments for this chunk
        const short* qbase = Q + ((size_t)(b * SEQ + qr)) * HD + lg * 8;
        bf16x8 qf0 = *(const bf16x8*)(qbase);
        bf16x8 qf1 = *(const bf16x8*)(qbase + 32);

        f32x4 o[4];   // o[df][j] = O[q=l15][d = df*16 + lg*4 + j]
        float m = -1e30f, lsum = 0.f;
#pragma unroll
        for (int df = 0; df < 4; ++df) o[df] = (f32x4){0.f, 0.f, 0.f, 0.f};

        int t = split;
        if (t < ntile) stageKV(t * 64, 0);
        __syncthreads();   // vmcnt(0) drained before barrier => staging visible

        int buf = 0;
        for (; t < ntile; t += NSPL) {
            if (t + NSPL < ntile) stageKV((t + NSPL) * 64, buf ^ 1);

            const int kv0 = t * 64;
            const char* kB = (const char*)lK[buf];
            const char* vB = (const char*)lV[buf];

            // ---- S^T = K Q^T: s[nf] holds col=q(l15), row=kv(nf*16+lg*4+j) ----
            f32x4 s[4];
#pragma unroll
            for (int nf = 0; nf < 4; ++nf) s[nf] = (f32x4){0.f, 0.f, 0.f, 0.f};
#pragma unroll
            for (int nf = 0; nf < 4; ++nf) {
                int br = nf * 16 + l15;
                int bs = (br & 7) << 4;
                bf16x8 kf0 = *(const bf16x8*)(kB + br * 128 + ((lg * 16) ^ bs));
                bf16x8 kf1 = *(const bf16x8*)(kB + br * 128 + ((lg * 16 + 64) ^ bs));
                s[nf] = __builtin_amdgcn_mfma_f32_16x16x32_bf16(kf0, qf0, s[nf], 0, 0, 0);
                s[nf] = __builtin_amdgcn_mfma_f32_16x16x32_bf16(kf1, qf1, s[nf], 0, 0, 0);
            }

            // ---- scale; mask only on the diagonal tile ----
            float sv[4][4];
            if (t == g) {
#pragma unroll
                for (int nf = 0; nf < 4; ++nf)
#pragma unroll
                    for (int j = 0; j < 4; ++j) {
                        int kv = kv0 + nf * 16 + lg * 4 + j;
                        float v = s[nf][j] * SC;
                        sv[nf][j] = (kv <= qr) ? v : -1e30f;
                    }
            } else {
#pragma unroll
                for (int nf = 0; nf < 4; ++nf)
#pragma unroll
                    for (int j = 0; j < 4; ++j) sv[nf][j] = s[nf][j] * SC;
            }

            // ---- row max: 15 in-lane + 2 cross-lg shuffles ----
            float m4[4];
#pragma unroll
            for (int nf = 0; nf < 4; ++nf)
                m4[nf] = fmaxf(fmaxf(sv[nf][0], sv[nf][1]), fmaxf(sv[nf][2], sv[nf][3]));
            float mt = fmaxf(fmaxf(m4[0], m4[1]), fmaxf(m4[2], m4[3]));
            mt = fmaxf(mt, __shfl_xor(mt, 16));
            mt = fmaxf(mt, __shfl_xor(mt, 32));

            // ---- online update (exp2 domain, scalar state) ----
            float mn = fmaxf(fmaxf(m, mt), -1e20f);
            float sf = exp2f(m - mn);
            m = mn;
            lsum *= sf;
#pragma unroll
            for (int df = 0; df < 4; ++df) o[df] *= sf;

            float p[4][4], rsum = 0.f;
#pragma unroll
            for (int nf = 0; nf < 4; ++nf) {
                float r4 = 0.f;
#pragma unroll
                for (int j = 0; j < 4; ++j) {
                    p[nf][j] = exp2f(sv[nf][j] - mn);
                    r4 += p[nf][j];
                }
                rsum += r4;
            }
            rsum += __shfl_xor(rsum, 16);
            rsum += __shfl_xor(rsum, 32);
            lsum += rsum;

            // ---- pack P (own q-row) into LDS: 4x ds_write_b64, swizzled ----
#pragma unroll
            for (int nf = 0; nf < 4; ++nf) {
                s16x4 pv;
                pv[0] = f2bn(p[nf][0]); pv[1] = f2bn(p[nf][1]);
                pv[2] = f2bn(p[nf][2]); pv[3] = f2bn(p[nf][3]);
                int off = (nf * 16 + lg * 4) * 2;
                *(s16x4*)(pw + l15 * 128 + (off ^ sw)) = pv;
            }

            bf16x8 pa0 = *(const bf16x8*)(pw + l15 * 128 + ((lg * 16) ^ sw));
            bf16x8 pa1 = *(const bf16x8*)(pw + l15 * 128 + ((lg * 16 + 64) ^ sw));

            // ---- O^T += V^T P^T (4 d-frags x 2 k-halves) ----
#pragma unroll
            for (int df = 0; df < 4; ++df) {
                int dr = df * 16 + l15;
                int ds = (dr & 7) << 4;
                bf16x8 vf0 = *(const bf16x8*)(vB + dr * 128 + ((lg * 16) ^ ds));
                bf16x8 vf1 = *(const bf16x8*)(vB + dr * 128 + ((lg * 16 + 64) ^ ds));
                o[df] = __builtin_amdgcn_mfma_f32_16x16x32_bf16(vf0, pa0, o[df], 0, 0, 0);
                o[df] = __builtin_amdgcn_mfma_f32_16x16x32_bf16(vf1, pa1, o[df], 0, 0, 0);
            }

            __syncthreads();   // all waves done with buf; next staging completed
            buf ^= 1;
        }

        // ---- epilogue: unnormalized partials; lane owns q-row qr ----
        {
            size_t R = (size_t)b * SEQ + qr;
            float* op = Opart + ((size_t)split * NROWS + R) * HD;
#pragma unroll
            for (int df = 0; df < 4; ++df)
                *(f32x4*)(op + df * 16 + lg * 4) = o[df];
            if (lg == 0) {
                mlbuf[((size_t)split * NROWS + R) * 2 + 0] = m;
                mlbuf[((size_t)split * NROWS + R) * 2 + 1] = lsum;
            }
        }
    }
}

// ---------------------------------------------------------------------------
// Kernel 3: merge 4 KV-split partials -> normalized output (exp2 domain).
// ---------------------------------------------------------------------------
__global__ __launch_bounds__(256) void merge_kernel(const float* __restrict__ Opart,
        const float* __restrict__ mlbuf, float* __restrict__ out) {
    int tg = blockIdx.x * 256 + threadIdx.x;   // 0 .. 262143
    int rr = tg >> 4;
    int fc = tg & 15;

    float mv[NSPL], lv[NSPL];
    float M = -3e38f;
#pragma unroll
    for (int i = 0; i < NSPL; ++i) {
        mv[i] = mlbuf[((size_t)i * NROWS + rr) * 2 + 0];
        lv[i] = mlbuf[((size_t)i * NROWS + rr) * 2 + 1];
        M = fmaxf(M, mv[i]);
    }
    float L = 0.f;
    f32x4 acc = (f32x4){0.f, 0.f, 0.f, 0.f};
#pragma unroll
    for (int i = 0; i < NSPL; ++i) {
        float w = exp2f(mv[i] - M);
        L += lv[i] * w;
        f32x4 v = *(const f32x4*)(Opart + ((size_t)i * NROWS + rr) * HD + fc * 4);
        acc += v * w;
    }
    f32x4 r = acc / L;
    *(f32x4*)(out + (size_t)rr * HD + fc * 4) = r;
}

// ---------------------------------------------------------------------------
extern "C" void kernel_launch(void* const* d_in, const int* in_sizes, int n_in,
                              void* d_out, int out_size, void* d_ws, size_t ws_size,
                              hipStream_t stream) {
    const float* x  = (const float*)d_in[0];
    const float* Wq = (const float*)d_in[1];
    const float* bq = (const float*)d_in[2];
    const float* Wk = (const float*)d_in[3];
    const float* bk = (const float*)d_in[4];
    const float* Wv = (const float*)d_in[5];
    const float* bv = (const float*)d_in[6];
    float* out = (float*)d_out;

    char* ws = (char*)d_ws;
    // Workspace layout (bytes):
    //   Wt    bf16 [192][1024]        @ 0         (393216)
    //   bias  f32  [192]              @ 393216    (768, pad to 394240)
    //   Q     bf16 [16384][64]        @ 394240    (2097152)
    //   K     bf16 [16384][64]        @ 2491392   (2097152)
    //   Vt    bf16 [8][64][2048]      @ 4588544   (2097152)
    //   Opart f32  [4][16384][64]     @ 6685696   (16777216)
    //   ml    f32  [4][16384][2]      @ 23462912  (524288)   end 23987200
    short* Wt   = (short*)(ws);
    float* bias = (float*)(ws + 393216);
    short* Qb   = (short*)(ws + 394240);
    short* Kb   = (short*)(ws + 394240 + 2097152);
    short* Vtb  = (short*)(ws + 394240 + 2 * 2097152);
    float* Op   = (float*)(ws + 6685696);
    float* ml   = (float*)(ws + 23462912);

    hipLaunchKernelGGL(prep_kernel, dim3(768), dim3(256), 0, stream,
                       Wq, bq, Wk, bk, Wv, bv, Wt, bias);
    hipLaunchKernelGGL(proj_kernel, dim3(1024), dim3(256), 0, stream,
                       x, Wt, bias, Qb, Kb, Vtb);
    hipLaunchKernelGGL(attn_kernel, dim3(512), dim3(256), 0, stream,
                       Qb, Kb, Vtb, Op, ml);
    hipLaunchKernelGGL(merge_kernel, dim3(1024), dim3(256), 0, stream,
                       Op, ml, out);
}